// Round 8
// baseline (224.275 us; speedup 1.0000x reference)
//
#include <hip/hip_runtime.h>
#include <math.h>

// EdgeFeatureEncoding: proj = edge_attr @ W + b (E x 8), scatter-add into
// dense (N, N, 8) bias at (i, j).
//
// Structure (3 graph nodes):
//   K0 zero counters/ocnt    ~2 us (rocclr small-fill is unreliable)
//   KF fused fill||proj+bin  2048 blocks, 3:1 interleave: bid%4==3 (512) does
//                            proj GEMM + chunk binning; else (1536) grid-
//                            stride nontemporal zero-fill of d_out. Best
//                            measured config: ~5.6-5.8 TB/s aggregate (R6).
//   K4' inject(+overflow)    16-lane group per chunk: merged per-cell sums,
//                            non-atomic 32 B stores onto zeroed cells; then
//                            the rare bin-overflow records (Poisson tail past
//                            BIN_CAP) are atomicAdd'ed by the owning block
//                            after __syncthreads + __threadfence.
// Fallback (odd shapes / small ws): memset + atomic scatter.

#define CHUNK_CELLS 1024   // cells per chunk (cell = 8 floats)
#define BIN_CAP     16     // slots per chunk; lambda ~= 8 here, tail -> ovf

typedef float f32x4 __attribute__((ext_vector_type(4)));

// ------------------------------------------------------------- K0: zero state
__global__ __launch_bounds__(256) void efe_zero_counters(unsigned* __restrict__ p,
                                                         int n) {
    const int i = blockIdx.x * blockDim.x + threadIdx.x;
    if (i < n) p[i] = 0u;
}

// ----------------------------------------- KF: fused fill || proj+bin kernel
__global__ __launch_bounds__(256) void efe_fused_kernel(
    const int* __restrict__ ei,      // (2, E): ei[e]=i, ei[E+e]=j
    const float* __restrict__ attr,  // (E, 128)
    const int* __restrict__ nn,      // num_nodes (device scalar)
    const float* __restrict__ Wm,    // (128, 8)
    const float* __restrict__ bv,    // (8,)
    float* __restrict__ proj,        // ws: (E, 8)
    unsigned* __restrict__ counters, // ws: (nchunks,) zeroed by K0
    unsigned* __restrict__ bins,     // ws: (nchunks, BIN_CAP) rec=(lc<<20)|e
    unsigned* __restrict__ ocnt,     // ws: overflow count (zeroed by K0)
    unsigned long long* __restrict__ ovf, // ws: overflow (cell<<32)|e
    float* __restrict__ out,         // (N, N, 8) -> zero-filled by fill role
    long n4,                         // out_size/4 float4s
    int E)
{
    const int bid = blockIdx.x;
    const int role_k1 = ((bid & 3) == 3);

    if (!role_k1) {
        // ---- fill role: 3 of every 4 blocks, grid-stride nontemporal zeros.
        const int fid = (bid >> 2) * 3 + (bid & 3);        // 0..nfill-1
        const int nfill = ((int)gridDim.x >> 2) * 3;
        const long stride = (long)nfill * blockDim.x;
        const f32x4 z = (f32x4)0.f;
        f32x4* o4 = (f32x4*)out;
        for (long i = (long)fid * blockDim.x + threadIdx.x; i < n4; i += stride)
            __builtin_nontemporal_store(z, &o4[i]);
        return;
    }

    // ---- proj+bin role: 1 of every 4 blocks.
    const int kid = bid >> 2;                              // 0..nk1-1
    const int nk1 = (int)gridDim.x >> 2;
    const int N = nn[0];
    const int tid    = kid * blockDim.x + threadIdx.x;
    const int wave   = tid >> 6;
    const int lane   = threadIdx.x & 63;
    const int lg     = lane & 15;
    const int sub    = lane >> 4;
    const int nwaves = (nk1 * blockDim.x) >> 6;

    // W slice in registers: rows k = half*64 + lg*4 + c.
    float w[2][4][8];
#pragma unroll
    for (int half = 0; half < 2; ++half)
#pragma unroll
        for (int c = 0; c < 4; ++c) {
            const int k = half * 64 + lg * 4 + c;
#pragma unroll
            for (int h = 0; h < 8; ++h) w[half][c][h] = Wm[k * 8 + h];
        }
    float bh[8];
#pragma unroll
    for (int h = 0; h < 8; ++h) bh[h] = bv[h];

    const int nquads = (E + 3) >> 2;
    for (int q = wave; q < nquads; q += nwaves) {
        const int e = q * 4 + sub;
        const bool live = (e < E);

        int i = 0, j = 0;
        if (live) { i = ei[e]; j = ei[E + e]; }

        float acc[8];
#pragma unroll
        for (int h = 0; h < 8; ++h) acc[h] = 0.f;

        if (live) {
            const float4* row = (const float4*)(attr + (size_t)e * 128);
#pragma unroll
            for (int half = 0; half < 2; ++half) {
                const float4 v = row[half * 16 + lg];
#pragma unroll
                for (int h = 0; h < 8; ++h)
                    acc[h] += v.x * w[half][0][h] + v.y * w[half][1][h]
                            + v.z * w[half][2][h] + v.w * w[half][3][h];
            }
        }
        // 16-lane group tree reduce (xor masks 1,2,4,8 stay in-group on wave64).
#pragma unroll
        for (int d = 1; d < 16; d <<= 1)
#pragma unroll
            for (int h = 0; h < 8; ++h)
                acc[h] += __shfl_xor(acc[h], d, 64);

        if (live && lg < 8) {
            float v = acc[0] + bh[0];
#pragma unroll
            for (int h = 1; h < 8; ++h) {
                const float cand = acc[h] + bh[h];
                v = (lg == h) ? cand : v;
            }
            proj[(size_t)e * 8 + lg] = v;
        }
        if (live && lg == 0) {
            if (i >= 0 && i < N && j >= 0 && j < N) {
                const long cell = (long)i * N + j;
                const unsigned chunk = (unsigned)(cell >> 10);   // /CHUNK_CELLS
                const unsigned lc    = (unsigned)(cell & 1023u);
                const unsigned pos = atomicAdd(&counters[chunk], 1u);
                if (pos < BIN_CAP)
                    bins[(size_t)chunk * BIN_CAP + pos] = (lc << 20) | (unsigned)e;
                else {
                    const unsigned op = atomicAdd(ocnt, 1u);
                    ovf[op] = ((unsigned long long)cell << 32) | (unsigned)e;
                }
            }
        }
    }
}

// ------------------------------- K4': sparse merged inject (store) + overflow
// One 16-lane group per chunk (16 chunks per block); cells are zero post-fill,
// so merged per-cell sums are plain stores. Overflow records for this block's
// chunks are atomicAdd'ed afterwards (ordering via syncthreads+threadfence).
__global__ __launch_bounds__(256) void efe_inject_kernel(
    const unsigned* __restrict__ counters,
    const unsigned* __restrict__ bins,
    const unsigned* __restrict__ ocnt,
    const unsigned long long* __restrict__ ovf,
    const float* __restrict__ proj,
    float* __restrict__ out,
    unsigned nchunks)
{
    const unsigned chunk = blockIdx.x * 16 + (threadIdx.x >> 4);
    const int slot = threadIdx.x & 15;

    if (chunk < nchunks) {
        unsigned cnt = counters[chunk];
        if (cnt > BIN_CAP) cnt = BIN_CAP;

        const unsigned myrec = bins[(size_t)chunk * BIN_CAP + slot];
        const int mylc = (int)(myrec >> 20);
        const bool act = (slot < (int)cnt);

        f32x4 s0 = (f32x4)0.f, s1 = (f32x4)0.f;
        bool dup = false;

#pragma unroll
        for (int s = 0; s < BIN_CAP; ++s) {
            const unsigned rs = __shfl(myrec, s, 16);     // record s of my group
            const bool slive = (s < (int)cnt);
            const int slc = (int)(rs >> 20);
            const unsigned se = rs & 0xFFFFFu;
            if (slive && act && slc == mylc) {
                if (s < slot) dup = true;                 // earlier same-cell owner
                else {                                    // accumulate s's proj
                    s0 += *(const f32x4*)(proj + (size_t)se * 8);
                    s1 += *(const f32x4*)(proj + (size_t)se * 8 + 4);
                }
            }
        }

        if (act && !dup) {
            float* cell = out + (((size_t)chunk << 10) + mylc) * 8;
            *(f32x4*)cell = s0;
            *(f32x4*)(cell + 4) = s1;
        }
    }

    // ---- overflow tail (usually oc == 0). Handled by the block owning the
    // target chunk, so the atomicAdd lands after that block's stores.
    const unsigned oc = *ocnt;                 // uniform load across block
    if (oc) {
        __syncthreads();
        __threadfence();
        const unsigned cbase = blockIdx.x * 16;
        const unsigned cend  = cbase + 16;
        const int h = threadIdx.x & 7;
        for (unsigned r = (unsigned)(threadIdx.x >> 3); r < oc; r += 32) {
            const unsigned long long rec = ovf[r];
            const long cell = (long)(rec >> 32);
            const unsigned rchunk = (unsigned)(cell >> 10);
            if (rchunk >= cbase && rchunk < cend) {
                const unsigned e = (unsigned)(rec & 0xFFFFFFFFu);
                atomicAdd(out + (size_t)cell * 8 + h, proj[(size_t)e * 8 + h]);
            }
        }
    }
}

// ------------------------------------------------------- fallback: atomic path
__global__ __launch_bounds__(256) void efe_scatter_kernel(
    const int* __restrict__ ei, const float* __restrict__ attr,
    const int* __restrict__ nn, const float* __restrict__ Wm,
    const float* __restrict__ bv, float* __restrict__ out, int E)
{
    const int N = nn[0];
    const int tid    = blockIdx.x * blockDim.x + threadIdx.x;
    const int wave   = tid >> 6;
    const int lane   = threadIdx.x & 63;
    const int lg     = lane & 15;
    const int sub    = lane >> 4;
    const int nwaves = (gridDim.x * blockDim.x) >> 6;

    float w[2][4][8];
#pragma unroll
    for (int half = 0; half < 2; ++half)
#pragma unroll
        for (int c = 0; c < 4; ++c) {
            const int k = half * 64 + lg * 4 + c;
#pragma unroll
            for (int h = 0; h < 8; ++h) w[half][c][h] = Wm[k * 8 + h];
        }
    float bh[8];
#pragma unroll
    for (int h = 0; h < 8; ++h) bh[h] = bv[h];

    const int nquads = (E + 3) >> 2;
    for (int q = wave; q < nquads; q += nwaves) {
        const int e = q * 4 + sub;
        const bool live = (e < E);
        int i = 0, j = 0;
        if (live) { i = ei[e]; j = ei[E + e]; }
        float acc[8];
#pragma unroll
        for (int h = 0; h < 8; ++h) acc[h] = 0.f;
        if (live) {
            const float4* row = (const float4*)(attr + (size_t)e * 128);
#pragma unroll
            for (int half = 0; half < 2; ++half) {
                const float4 v = row[half * 16 + lg];
#pragma unroll
                for (int h = 0; h < 8; ++h)
                    acc[h] += v.x * w[half][0][h] + v.y * w[half][1][h]
                            + v.z * w[half][2][h] + v.w * w[half][3][h];
            }
        }
#pragma unroll
        for (int d = 1; d < 16; d <<= 1)
#pragma unroll
            for (int h = 0; h < 8; ++h)
                acc[h] += __shfl_xor(acc[h], d, 64);
        if (live && lg < 8 && i >= 0 && i < N && j >= 0 && j < N) {
            float v = acc[0] + bh[0];
#pragma unroll
            for (int h = 1; h < 8; ++h) {
                const float cand = acc[h] + bh[h];
                v = (lg == h) ? cand : v;
            }
            atomicAdd(out + (((size_t)i * N + j) << 3) + lg, v);
        }
    }
}

extern "C" void kernel_launch(void* const* d_in, const int* in_sizes, int n_in,
                              void* d_out, int out_size, void* d_ws, size_t ws_size,
                              hipStream_t stream) {
    const int*   ei   = (const int*)d_in[0];
    const float* attr = (const float*)d_in[1];
    const int*   nn   = (const int*)d_in[2];
    const float* Wm   = (const float*)d_in[3];
    const float* bv   = (const float*)d_in[4];
    float*       out  = (float*)d_out;

    const int E = in_sizes[0] / 2;

    // Host-side geometry: out_size = N*N*8 (host doesn't see num_nodes' value).
    const long ncells = (long)out_size / 8;
    const long Nh = (long)(sqrt((double)ncells) + 0.5);
    const bool shape_ok = (Nh * Nh == ncells) && (ncells % CHUNK_CELLS == 0) &&
                          (E > 0) && (E <= (1 << 20));

    // ws layout (256B-aligned regions)
    const size_t nchunks = (size_t)(ncells / CHUNK_CELLS);
    const size_t o_cnt  = 0;                       // counters: nchunks u32
    const size_t o_ocnt = nchunks * 4;             // ocnt: 1 u32 (contiguous)
    const size_t o_ovf  = ((o_ocnt + 4 + 255) / 256) * 256;
    const size_t o_proj = ((o_ovf + (size_t)E * 8 + 255) / 256) * 256;
    const size_t o_bins = ((o_proj + (size_t)E * 32 + 255) / 256) * 256;
    const size_t need   = o_bins + nchunks * BIN_CAP * 4;

    if (shape_ok && ws_size >= need) {
        unsigned* counters = (unsigned*)((char*)d_ws + o_cnt);
        unsigned* ocnt     = (unsigned*)((char*)d_ws + o_ocnt);
        unsigned long long* ovf = (unsigned long long*)((char*)d_ws + o_ovf);
        float*    proj     = (float*)((char*)d_ws + o_proj);
        unsigned* bins     = (unsigned*)((char*)d_ws + o_bins);

        const int nzero = (int)nchunks + 1;        // counters + ocnt
        efe_zero_counters<<<(nzero + 255) / 256, 256, 0, stream>>>(counters, nzero);

        // Fused fill || proj+bin. 2048 blocks, fine 3:1 role interleave
        // (R6 best-measured config — unchanged).
        const long n4 = (long)out_size / 4;
        efe_fused_kernel<<<2048, 256, 0, stream>>>(
            ei, attr, nn, Wm, bv, proj, counters, bins, ocnt, ovf, out, n4, E);

        const unsigned injblocks = (unsigned)((nchunks + 15) / 16);
        efe_inject_kernel<<<injblocks, 256, 0, stream>>>(
            counters, bins, ocnt, ovf, proj, out, (unsigned)nchunks);
    } else {
        // Fallback: memset node + atomic scatter.
        hipMemsetAsync(d_out, 0, (size_t)out_size * sizeof(float), stream);
        efe_scatter_kernel<<<2048, 256, 0, stream>>>(ei, attr, nn, Wm, bv, out, E);
    }
}

// Round 9
// 120.950 us; speedup vs baseline: 1.8543x; 1.8543x over previous
//
#include <hip/hip_runtime.h>
#include <math.h>

// EdgeFeatureEncoding: proj = edge_attr @ W + b (E x 8), scatter-add into
// dense (N, N, 8) bias at (i, j).
//
// Structure (3 graph nodes):
//   K0 zero counters/ocnt    ~2 us
//   KF fused fill||proj+bin  2048 blocks, 3:1 interleave: bid%4==3 (512) does
//                            proj GEMM + chunk binning; else (1536) grid-
//                            stride nontemporal zero-fill of d_out.
//                            (R6 best-measured config, byte-identical.)
//   K4' inject(+overflow)    32-lane group per chunk: merged per-cell sums,
//                            non-atomic 32 B stores onto zeroed cells.
//                            BIN_CAP=32 makes bin overflow structurally
//                            impossible for lambda~=8 (P ~ 1e-12/chunk), so
//                            the fence-guarded overflow branch (kept for
//                            arbitrary-input correctness) never executes.
//                            R8 lesson: a __threadfence on the per-block
//                            common path (oc>0 with BIN_CAP=16) cost +103 us
//                            -- device-scope fence = L2 writeback per block.
// Fallback (odd shapes / small ws): memset + atomic scatter.

#define CHUNK_CELLS 1024   // cells per chunk (cell = 8 floats)
#define BIN_CAP     32     // slots per chunk; lambda ~= 8 -> overflow never

typedef float f32x4 __attribute__((ext_vector_type(4)));

// ------------------------------------------------------------- K0: zero state
__global__ __launch_bounds__(256) void efe_zero_counters(unsigned* __restrict__ p,
                                                         int n) {
    const int i = blockIdx.x * blockDim.x + threadIdx.x;
    if (i < n) p[i] = 0u;
}

// ----------------------------------------- KF: fused fill || proj+bin kernel
__global__ __launch_bounds__(256) void efe_fused_kernel(
    const int* __restrict__ ei,      // (2, E): ei[e]=i, ei[E+e]=j
    const float* __restrict__ attr,  // (E, 128)
    const int* __restrict__ nn,      // num_nodes (device scalar)
    const float* __restrict__ Wm,    // (128, 8)
    const float* __restrict__ bv,    // (8,)
    float* __restrict__ proj,        // ws: (E, 8)
    unsigned* __restrict__ counters, // ws: (nchunks,) zeroed by K0
    unsigned* __restrict__ bins,     // ws: (nchunks, BIN_CAP) rec=(lc<<20)|e
    unsigned* __restrict__ ocnt,     // ws: overflow count (zeroed by K0)
    unsigned long long* __restrict__ ovf, // ws: overflow (cell<<32)|e
    float* __restrict__ out,         // (N, N, 8) -> zero-filled by fill role
    long n4,                         // out_size/4 float4s
    int E)
{
    const int bid = blockIdx.x;
    const int role_k1 = ((bid & 3) == 3);

    if (!role_k1) {
        // ---- fill role: 3 of every 4 blocks, grid-stride nontemporal zeros.
        const int fid = (bid >> 2) * 3 + (bid & 3);        // 0..nfill-1
        const int nfill = ((int)gridDim.x >> 2) * 3;
        const long stride = (long)nfill * blockDim.x;
        const f32x4 z = (f32x4)0.f;
        f32x4* o4 = (f32x4*)out;
        for (long i = (long)fid * blockDim.x + threadIdx.x; i < n4; i += stride)
            __builtin_nontemporal_store(z, &o4[i]);
        return;
    }

    // ---- proj+bin role: 1 of every 4 blocks.
    const int kid = bid >> 2;                              // 0..nk1-1
    const int nk1 = (int)gridDim.x >> 2;
    const int N = nn[0];
    const int tid    = kid * blockDim.x + threadIdx.x;
    const int wave   = tid >> 6;
    const int lane   = threadIdx.x & 63;
    const int lg     = lane & 15;
    const int sub    = lane >> 4;
    const int nwaves = (nk1 * blockDim.x) >> 6;

    // W slice in registers: rows k = half*64 + lg*4 + c.
    float w[2][4][8];
#pragma unroll
    for (int half = 0; half < 2; ++half)
#pragma unroll
        for (int c = 0; c < 4; ++c) {
            const int k = half * 64 + lg * 4 + c;
#pragma unroll
            for (int h = 0; h < 8; ++h) w[half][c][h] = Wm[k * 8 + h];
        }
    float bh[8];
#pragma unroll
    for (int h = 0; h < 8; ++h) bh[h] = bv[h];

    const int nquads = (E + 3) >> 2;
    for (int q = wave; q < nquads; q += nwaves) {
        const int e = q * 4 + sub;
        const bool live = (e < E);

        int i = 0, j = 0;
        if (live) { i = ei[e]; j = ei[E + e]; }

        float acc[8];
#pragma unroll
        for (int h = 0; h < 8; ++h) acc[h] = 0.f;

        if (live) {
            const float4* row = (const float4*)(attr + (size_t)e * 128);
#pragma unroll
            for (int half = 0; half < 2; ++half) {
                const float4 v = row[half * 16 + lg];
#pragma unroll
                for (int h = 0; h < 8; ++h)
                    acc[h] += v.x * w[half][0][h] + v.y * w[half][1][h]
                            + v.z * w[half][2][h] + v.w * w[half][3][h];
            }
        }
        // 16-lane group tree reduce (xor masks 1,2,4,8 stay in-group on wave64).
#pragma unroll
        for (int d = 1; d < 16; d <<= 1)
#pragma unroll
            for (int h = 0; h < 8; ++h)
                acc[h] += __shfl_xor(acc[h], d, 64);

        if (live && lg < 8) {
            float v = acc[0] + bh[0];
#pragma unroll
            for (int h = 1; h < 8; ++h) {
                const float cand = acc[h] + bh[h];
                v = (lg == h) ? cand : v;
            }
            proj[(size_t)e * 8 + lg] = v;
        }
        if (live && lg == 0) {
            if (i >= 0 && i < N && j >= 0 && j < N) {
                const long cell = (long)i * N + j;
                const unsigned chunk = (unsigned)(cell >> 10);   // /CHUNK_CELLS
                const unsigned lc    = (unsigned)(cell & 1023u);
                const unsigned pos = atomicAdd(&counters[chunk], 1u);
                if (pos < BIN_CAP)
                    bins[(size_t)chunk * BIN_CAP + pos] = (lc << 20) | (unsigned)e;
                else {
                    const unsigned op = atomicAdd(ocnt, 1u);
                    ovf[op] = ((unsigned long long)cell << 32) | (unsigned)e;
                }
            }
        }
    }
}

// ------------------------------- K4': sparse merged inject (store) + overflow
// One 32-lane group per chunk (8 chunks per block); cells are zero post-fill,
// so merged per-cell sums are plain stores. shfl masks 1..16 stay within the
// 32-lane group on wave64. The overflow branch never executes for BIN_CAP=32
// (kept for arbitrary-input correctness only).
__global__ __launch_bounds__(256) void efe_inject_kernel(
    const unsigned* __restrict__ counters,
    const unsigned* __restrict__ bins,
    const unsigned* __restrict__ ocnt,
    const unsigned long long* __restrict__ ovf,
    const float* __restrict__ proj,
    float* __restrict__ out,
    unsigned nchunks)
{
    const unsigned chunk = blockIdx.x * 8 + (threadIdx.x >> 5);
    const int slot = threadIdx.x & 31;

    if (chunk < nchunks) {
        unsigned cnt = counters[chunk];
        if (cnt > BIN_CAP) cnt = BIN_CAP;

        // Coalesced: thread tid loads bins[blockbase*32 + tid] (1 KiB/block).
        const unsigned myrec = bins[(size_t)chunk * BIN_CAP + slot];
        const int mylc = (int)(myrec >> 20);
        const bool act = (slot < (int)cnt);

        f32x4 s0 = (f32x4)0.f, s1 = (f32x4)0.f;
        bool dup = false;

#pragma unroll
        for (int s = 0; s < BIN_CAP; ++s) {
            const unsigned rs = __shfl(myrec, s, 32);     // record s of my group
            const bool slive = (s < (int)cnt);
            const int slc = (int)(rs >> 20);
            const unsigned se = rs & 0xFFFFFu;
            if (slive && act && slc == mylc) {
                if (s < slot) dup = true;                 // earlier same-cell owner
                else {                                    // accumulate s's proj
                    s0 += *(const f32x4*)(proj + (size_t)se * 8);
                    s1 += *(const f32x4*)(proj + (size_t)se * 8 + 4);
                }
            }
        }

        if (act && !dup) {
            float* cell = out + (((size_t)chunk << 10) + mylc) * 8;
            *(f32x4*)cell = s0;
            *(f32x4*)(cell + 4) = s1;
        }
    }

    // ---- overflow tail: oc == 0 for BIN_CAP=32 at lambda~=8 (P ~ 1e-12 per
    // chunk), so this branch is dead on the bench input. Kept for correctness
    // on arbitrary inputs; fence cost only paid when overflow actually exists.
    const unsigned oc = *ocnt;                 // uniform load across block
    if (oc) {
        __syncthreads();
        __threadfence();
        const unsigned cbase = blockIdx.x * 8;
        const unsigned cend  = cbase + 8;
        const int h = threadIdx.x & 7;
        for (unsigned r = (unsigned)(threadIdx.x >> 3); r < oc; r += 32) {
            const unsigned long long rec = ovf[r];
            const long cell = (long)(rec >> 32);
            const unsigned rchunk = (unsigned)(cell >> 10);
            if (rchunk >= cbase && rchunk < cend) {
                const unsigned e = (unsigned)(rec & 0xFFFFFFFFu);
                atomicAdd(out + (size_t)cell * 8 + h, proj[(size_t)e * 8 + h]);
            }
        }
    }
}

// ------------------------------------------------------- fallback: atomic path
__global__ __launch_bounds__(256) void efe_scatter_kernel(
    const int* __restrict__ ei, const float* __restrict__ attr,
    const int* __restrict__ nn, const float* __restrict__ Wm,
    const float* __restrict__ bv, float* __restrict__ out, int E)
{
    const int N = nn[0];
    const int tid    = blockIdx.x * blockDim.x + threadIdx.x;
    const int wave   = tid >> 6;
    const int lane   = threadIdx.x & 63;
    const int lg     = lane & 15;
    const int sub    = lane >> 4;
    const int nwaves = (gridDim.x * blockDim.x) >> 6;

    float w[2][4][8];
#pragma unroll
    for (int half = 0; half < 2; ++half)
#pragma unroll
        for (int c = 0; c < 4; ++c) {
            const int k = half * 64 + lg * 4 + c;
#pragma unroll
            for (int h = 0; h < 8; ++h) w[half][c][h] = Wm[k * 8 + h];
        }
    float bh[8];
#pragma unroll
    for (int h = 0; h < 8; ++h) bh[h] = bv[h];

    const int nquads = (E + 3) >> 2;
    for (int q = wave; q < nquads; q += nwaves) {
        const int e = q * 4 + sub;
        const bool live = (e < E);
        int i = 0, j = 0;
        if (live) { i = ei[e]; j = ei[E + e]; }
        float acc[8];
#pragma unroll
        for (int h = 0; h < 8; ++h) acc[h] = 0.f;
        if (live) {
            const float4* row = (const float4*)(attr + (size_t)e * 128);
#pragma unroll
            for (int half = 0; half < 2; ++half) {
                const float4 v = row[half * 16 + lg];
#pragma unroll
                for (int h = 0; h < 8; ++h)
                    acc[h] += v.x * w[half][0][h] + v.y * w[half][1][h]
                            + v.z * w[half][2][h] + v.w * w[half][3][h];
            }
        }
#pragma unroll
        for (int d = 1; d < 16; d <<= 1)
#pragma unroll
            for (int h = 0; h < 8; ++h)
                acc[h] += __shfl_xor(acc[h], d, 64);
        if (live && lg < 8 && i >= 0 && i < N && j >= 0 && j < N) {
            float v = acc[0] + bh[0];
#pragma unroll
            for (int h = 1; h < 8; ++h) {
                const float cand = acc[h] + bh[h];
                v = (lg == h) ? cand : v;
            }
            atomicAdd(out + (((size_t)i * N + j) << 3) + lg, v);
        }
    }
}

extern "C" void kernel_launch(void* const* d_in, const int* in_sizes, int n_in,
                              void* d_out, int out_size, void* d_ws, size_t ws_size,
                              hipStream_t stream) {
    const int*   ei   = (const int*)d_in[0];
    const float* attr = (const float*)d_in[1];
    const int*   nn   = (const int*)d_in[2];
    const float* Wm   = (const float*)d_in[3];
    const float* bv   = (const float*)d_in[4];
    float*       out  = (float*)d_out;

    const int E = in_sizes[0] / 2;

    // Host-side geometry: out_size = N*N*8 (host doesn't see num_nodes' value).
    const long ncells = (long)out_size / 8;
    const long Nh = (long)(sqrt((double)ncells) + 0.5);
    const bool shape_ok = (Nh * Nh == ncells) && (ncells % CHUNK_CELLS == 0) &&
                          (E > 0) && (E <= (1 << 20));

    // ws layout (256B-aligned regions)
    const size_t nchunks = (size_t)(ncells / CHUNK_CELLS);
    const size_t o_cnt  = 0;                       // counters: nchunks u32
    const size_t o_ocnt = nchunks * 4;             // ocnt: 1 u32 (contiguous)
    const size_t o_ovf  = ((o_ocnt + 4 + 255) / 256) * 256;
    const size_t o_proj = ((o_ovf + (size_t)E * 8 + 255) / 256) * 256;
    const size_t o_bins = ((o_proj + (size_t)E * 32 + 255) / 256) * 256;
    const size_t need   = o_bins + nchunks * BIN_CAP * 4;

    if (shape_ok && ws_size >= need) {
        unsigned* counters = (unsigned*)((char*)d_ws + o_cnt);
        unsigned* ocnt     = (unsigned*)((char*)d_ws + o_ocnt);
        unsigned long long* ovf = (unsigned long long*)((char*)d_ws + o_ovf);
        float*    proj     = (float*)((char*)d_ws + o_proj);
        unsigned* bins     = (unsigned*)((char*)d_ws + o_bins);

        const int nzero = (int)nchunks + 1;        // counters + ocnt
        efe_zero_counters<<<(nzero + 255) / 256, 256, 0, stream>>>(counters, nzero);

        // Fused fill || proj+bin. 2048 blocks, fine 3:1 role interleave
        // (R6 best-measured config — unchanged).
        const long n4 = (long)out_size / 4;
        efe_fused_kernel<<<2048, 256, 0, stream>>>(
            ei, attr, nn, Wm, bv, proj, counters, bins, ocnt, ovf, out, n4, E);

        const unsigned injblocks = (unsigned)((nchunks + 7) / 8);
        efe_inject_kernel<<<injblocks, 256, 0, stream>>>(
            counters, bins, ocnt, ovf, proj, out, (unsigned)nchunks);
    } else {
        // Fallback: memset node + atomic scatter.
        hipMemsetAsync(d_out, 0, (size_t)out_size * sizeof(float), stream);
        efe_scatter_kernel<<<2048, 256, 0, stream>>>(ei, attr, nn, Wm, bv, out, E);
    }
}